// Round 8
// baseline (58.923 us; speedup 1.0000x reference)
//
#include <hip/hip_runtime.h>
#include <math.h>

// ---- problem constants -------------------------------------------------
#define BB   4      // batch
#define NN   128    // sites
#define NPP  16     // pores
#define EEE  1280   // ss edges
#define ESP  1024   // sp/ps edges
#define DD   32     // node feat dim
#define CC   16     // gaussian centers / edge feat dim
#define OO   32     // message dim
#define FIN  80     // 2*DD + CC
#define MMM  64     // head hidden
#define TT   3      // message passing steps
#define TPB  256    // init block
#define SPB  512    // step block

#define MAXDEG_SS 48    // ss/ps: mean deg 10/8 (Binomial max ~26)
#define MAXDEG_SP 192   // sp: mean deg 64 (max ~95)

// ---- workspace layout (floats) ----------------------------------------
constexpr int OFF_S    = 0;                        // site states   [B*N*32]
constexpr int OFF_SP   = OFF_S   + BB*NN*DD;       // pore states   [B*Np*32]
constexpr int OFF_BE   = OFF_SP  + BB*NPP*DD;      // ss edge feats [B*E*16]
constexpr int OFF_BSP  = OFF_BE  + BB*EEE*CC;      // sp edge feats
constexpr int OFF_BPS  = OFF_BSP + BB*ESP*CC;      // ps edge feats
constexpr int OFF_PRJ  = OFF_BPS + BB*ESP*CC;      // 2x parity proj buffers
constexpr int P_SASS = 0;                          // s  @ (W1+W2)_ss rows 0..31
constexpr int P_SBSS = P_SASS + BB*NN*OO;          // s  @ rows 32..63 (ss)
constexpr int P_SBPS = P_SBSS + BB*NN*OO;          // s  @ rows 32..63 (ps)
constexpr int P_SASP = P_SBPS + BB*NN*OO;          // s  @ rows 0..31  (sp)
constexpr int P_PAPS = P_SASP + BB*NN*OO;          // sp @ rows 0..31  (ps)
constexpr int P_PBSP = P_PAPS + BB*NPP*OO;         // sp @ rows 32..63 (sp)
constexpr int PRJ_SZ = P_PBSP + BB*NPP*OO;
constexpr int OFF_POOL = OFF_PRJ + 2*PRJ_SZ;       // pooled lrelu(s@p1W+b) [B*M]
constexpr int OFF_CSR  = OFF_POOL + BB*MMM;        // int region (even offset)
// int layout (relative to OFF_CSR):
constexpr int SS_CNT  = 0;                          // [128]
constexpr int PS_CNT  = SS_CNT + NN;                // [128]
constexpr int SP_CNT  = PS_CNT + NN;                // [16]
constexpr int TICKET  = SP_CNT + NPP;               // [1]
constexpr int SS_PAIR = 274;                        // int2[128*48]  (even)
constexpr int PS_PAIR = SS_PAIR + NN*MAXDEG_SS*2;   // int2[128*48]
constexpr int SP_PAIR = PS_PAIR + NN*MAXDEG_SS*2;   // int2[16*192]

__device__ __forceinline__ float lrelu(float x) { return x > 0.f ? x : 0.01f * x; }

__device__ __forceinline__ float dot16r(const float* ef, const float* we) {
    float4 f0 = *(const float4*)(ef);
    float4 f1 = *(const float4*)(ef + 4);
    float4 f2 = *(const float4*)(ef + 8);
    float4 f3 = *(const float4*)(ef + 12);
    return f0.x*we[ 0] + f0.y*we[ 1] + f0.z*we[ 2] + f0.w*we[ 3]
         + f1.x*we[ 4] + f1.y*we[ 5] + f1.z*we[ 6] + f1.w*we[ 7]
         + f2.x*we[ 8] + f2.y*we[ 9] + f2.z*we[10] + f2.w*we[11]
         + f3.x*we[12] + f3.y*we[13] + f3.z*we[14] + f3.w*we[15];
}

__device__ __forceinline__ float red32(float r) {
#pragma unroll
    for (int mm = 16; mm > 0; mm >>= 1) r += __shfl_xor(r, mm, 32);
    return r;
}

__device__ __forceinline__ void edge_embed(float d, const float* W, const float* bvec, float* out) {
    float g[CC];
#pragma unroll
    for (int c = 0; c < CC; ++c) {
        float mu = (10.0f / 15.0f) * (float)c;  // linspace(0,10,16), WIDTH=1
        float z = d - mu;
        g[c] = expf(-z * z);
    }
#pragma unroll
    for (int j = 0; j < CC; ++j) {
        float a = bvec[j];
#pragma unroll
        for (int c = 0; c < CC; ++c) a += g[c] * W[c * CC + j];
        out[j] = lrelu(a);
    }
}

// wave-ballot CSR build; stores (edge, sender) pairs. Deterministic.
__device__ __forceinline__ void csr_wave(const int* recv, const int* send, int E, int r,
                                         int* cnt, int2* pair, int maxdeg, int lane) {
    int base = 0;
    for (int c = 0; c < E; c += 64) {
        const int e = c + lane;
        const bool m = (recv[e] == r);
        const unsigned long long mask = __ballot(m);
        if (m) {
            const int pos = base + __popcll(mask & ((1ull << lane) - 1ull));
            if (pos < maxdeg) pair[pos] = make_int2(e, send[e]);
        }
        base += (int)__popcll(mask);
    }
    if (lane == 0) cnt[r] = base < maxdeg ? base : maxdeg;
}

// ---- K0: pool/ticket-zero + edge embeds + node embeds + t0 proj + CSR --
__global__ __launch_bounds__(TPB) void k_init(
    const float* sites, const float* bonds, const float* sites_p,
    const float* bonds_sp, const float* bonds_ps,
    const int* idx1, const int* idx2, const int* idx1_ps, const int* idx2_ps,
    const int* idx1_sp, const int* idx2_sp,
    const float* se_W, const float* se_b, const float* sep_W, const float* sep_b,
    const float* ee_W, const float* ee_b, const float* eep_W, const float* eep_b,
    const float* eqW1_ss, const float* eqW2_ss,
    const float* eqW1_ps, const float* eqW2_ps,
    const float* eqW1_sp, const float* eqW2_sp,
    float* ws)
{
    __shared__ float smem[4416];
    const int blk = blockIdx.x;
    const int tid = threadIdx.x;
    int* csr = (int*)(ws + OFF_CSR);

    if (blk == 0 && tid == 0) csr[TICKET] = 0;

    // part A: zero pool + edge-feature embeddings
    if (blk < 253) {
        const int totalA = BB*MMM + BB*EEE + BB*ESP + BB*ESP;
        for (int i = blk*TPB + tid; i < totalA; i += 253*TPB) {
            int r = i;
            if (r < BB*MMM) { ws[OFF_POOL + r] = 0.f; continue; }
            r -= BB*MMM;
            if (r < BB*EEE) { edge_embed(bonds[r],    ee_W,  ee_b,  ws + OFF_BE  + r*CC); continue; }
            r -= BB*EEE;
            if (r < BB*ESP) { edge_embed(bonds_sp[r], eep_W, eep_b, ws + OFF_BSP + r*CC); continue; }
            r -= BB*ESP;
            edge_embed(bonds_ps[r], eep_W, eep_b, ws + OFF_BPS + r*CC);
        }
    }
    // part B: node embeddings + t=0 projections
    if (blk < 72) {
        float* prj0 = ws + OFF_PRJ;
        const int el = tid >> 5, o = tid & 31;
        float* sP   = smem;
        float* sRow = smem + 4160;
        if (blk < 64) {                // sites
            const int g = blk*8 + el;
            float x = sites[g];
            float v0 = lrelu(x * se_W[o] + se_b[o]);
            ws[OFF_S + g*DD + o] = v0;
            sRow[el*32 + o] = v0;
            for (int i2 = tid; i2 < 4096; i2 += TPB) {
                int m = i2 >> 10, j = i2 & 1023, d = j >> 5, oo = j & 31;
                int row = (m == 1 || m == 2) ? (DD + d) : d;
                float wv;
                if (m < 2)      wv = eqW1_ss[row*OO + oo] + eqW2_ss[row*OO + oo];
                else if (m==2)  wv = eqW1_ps[row*OO + oo] + eqW2_ps[row*OO + oo];
                else            wv = eqW1_sp[row*OO + oo] + eqW2_sp[row*OO + oo];
                sP[i2] = wv;
            }
            __syncthreads();
            float p0=0.f,p1=0.f,p2=0.f,p3=0.f;
#pragma unroll
            for (int d = 0; d < 32; ++d) {
                float sv = sRow[el*32 + d];
                p0 += sv * sP[        d*32 + o];
                p1 += sv * sP[1024 +  d*32 + o];
                p2 += sv * sP[2048 +  d*32 + o];
                p3 += sv * sP[3072 +  d*32 + o];
            }
            prj0[P_SASS + g*OO + o] = p0;
            prj0[P_SBSS + g*OO + o] = p1;
            prj0[P_SBPS + g*OO + o] = p2;
            prj0[P_SASP + g*OO + o] = p3;
        } else {                       // pores
            const int g = (blk-64)*8 + el;
            float x0 = sites_p[g*2], x1 = sites_p[g*2+1];
            float v0 = lrelu(x0 * sep_W[o] + x1 * sep_W[DD + o] + sep_b[o]);
            ws[OFF_SP + g*DD + o] = v0;
            sRow[el*32 + o] = v0;
            for (int i2 = tid; i2 < 2048; i2 += TPB) {
                int m = i2 >> 10, j = i2 & 1023, d = j >> 5, oo = j & 31;
                int row = (m == 0) ? d : (DD + d);
                float wv;
                if (m == 0) wv = eqW1_ps[row*OO + oo] + eqW2_ps[row*OO + oo];
                else        wv = eqW1_sp[row*OO + oo] + eqW2_sp[row*OO + oo];
                sP[i2] = wv;
            }
            __syncthreads();
            float p0=0.f,p1=0.f;
#pragma unroll
            for (int d = 0; d < 32; ++d) {
                float sv = sRow[el*32 + d];
                p0 += sv * sP[        d*32 + o];
                p1 += sv * sP[1024 +  d*32 + o];
            }
            prj0[P_PAPS + g*OO + o] = p0;
            prj0[P_PBSP + g*OO + o] = p1;
        }
    }
    // part C: wave-ballot CSR pair build (blocks 72..139, 4 waves each)
    if (blk >= 72 && blk < 140) {
        const int widx = (blk - 72) * 4 + (tid >> 6);
        const int lane = tid & 63;
        if (widx < NN) {
            csr_wave(idx2, idx1, EEE, widx, csr + SS_CNT,
                     (int2*)(csr + SS_PAIR) + widx*MAXDEG_SS, MAXDEG_SS, lane);
        } else if (widx < 2*NN) {
            const int r = widx - NN;
            csr_wave(idx2_ps, idx1_ps, ESP, r, csr + PS_CNT,
                     (int2*)(csr + PS_PAIR) + r*MAXDEG_SS, MAXDEG_SS, lane);
        } else if (widx < 2*NN + NPP) {
            const int r = widx - 2*NN;
            csr_wave(idx2_sp, idx1_sp, ESP, r, csr + SP_CNT,
                     (int2*)(csr + SP_PAIR) + r*MAXDEG_SP, MAXDEG_SP, lane);
        }
    }
}

// ---- K1: fused step, one receiver per block ----------------------------
// grid = 576 x 512: blocks 0..511 site receivers (8 groups ss || 8 groups ps),
//                   blocks 512..575 pore receivers (16 groups sp).
__global__ __launch_bounds__(SPB) void k_step(
    const float* eqW1_ss, const float* eqW2_ss, const float* eqb_ss, const float* aw_ss, const float* ab_ss,
    const float* eqW1_ps, const float* eqW2_ps, const float* eqb_ps, const float* aw_ps, const float* ab_ps,
    const float* eqW1_sp, const float* eqW2_sp, const float* eqb_sp, const float* aw_sp, const float* ab_sp,
    const float* nuW1, const float* nub1, const float* nuW2, const float* nub2,
    const float* nupW1, const float* nupb1, const float* nupW2, const float* nupb2,
    const float* p1W, const float* p1b,
    const float* p2aW, const float* p2ab, const float* p2bW, const float* p2bb,
    const float* p3W, const float* p3b,
    float* ws, float* out, int t)
{
    __shared__ float sRed[768];       // 16x32 partials; reused as head scratch
    __shared__ float sH[96], sU[32], sSnew[32];
    __shared__ float sHy[256], sHz[256];
    __shared__ int sWin;
    const int tid = threadIdx.x, blk = blockIdx.x;
    const int slot = tid >> 5, o = tid & 31;
    const int par = t & 1;
    const float* PRJ  = ws + OFF_PRJ + par * PRJ_SZ;
    float*       PRJn = ws + OFF_PRJ + (par ^ 1) * PRJ_SZ;
    const int* csr = (const int*)(ws + OFF_CSR);

    if (blk < 512) {
        // ================= site receiver =================
        const int g = blk, b = g >> 7, n = g & 127;
        const bool is_ss = slot < 8;
        const int q = slot & 7;
        // per-thread stream constants (registers)
        const float* w1p = is_ss ? eqW1_ss : eqW1_ps;
        const float* w2p = is_ss ? eqW2_ss : eqW2_ps;
        const float* wa = w1p + t*FIN*OO + 2*DD*OO + o;
        const float* wb = w2p + t*FIN*OO + 2*DD*OO + o;
        float we[16];
#pragma unroll
        for (int c = 0; c < 16; ++c) we[c] = wa[c*OO] + wb[c*OO];
        const float bias = (is_ss ? eqb_ss : eqb_ps)[t*OO + o];
        const float awo  = (is_ss ? aw_ss  : aw_ps )[t*OO + o];
        const float abv  = (is_ss ? ab_ss  : ab_ps )[t];
        const float sb   = PRJ[(is_ss ? P_SBSS : P_SBPS) + g*OO + o];
        const float* SAb = is_ss ? (PRJ + P_SASS + b*(NN*OO))
                                 : (PRJ + P_PAPS + b*(NPP*OO));
        const float* EFb = is_ss ? (ws + OFF_BE  + b*(EEE*CC))
                                 : (ws + OFF_BPS + b*(ESP*CC));
        const int cnt = is_ss ? csr[SS_CNT + n] : csr[PS_CNT + n];
        const int2* lst = is_ss ? ((const int2*)(csr + SS_PAIR) + n*MAXDEG_SS)
                                : ((const int2*)(csr + PS_PAIR) + n*MAXDEG_SS);
        float acc = 0.f;
        for (int k = q; k < cnt; k += 8) {
            const int2 es = lst[k];
            float a = bias + sb + SAb[es.y*OO + o] + dot16r(EFb + es.x*CC, we);
            float u = lrelu(a);
            float rr = red32(u * awo);
            acc += u / (1.f + expf(-(rr + abv)));
        }
        sRed[slot*32 + o] = acc;
        if (tid < 32) sH[tid] = ws[OFF_S + g*DD + tid];
        __syncthreads();
        if (tid < 64) {
            const int r2 = tid >> 5, oo = tid & 31;
            float mv = 0.f;
#pragma unroll
            for (int j = 0; j < 8; ++j) mv += sRed[(r2*8 + j)*32 + oo];
            sH[32 + r2*32 + oo] = mv;
        }
        __syncthreads();
        if (tid < 32) {
            const float* W1 = nuW1 + t*(96*32);
            float a = nub1[t*32 + tid];
#pragma unroll
            for (int f = 0; f < 96; ++f) a += sH[f] * W1[f*32 + tid];
            sU[tid] = lrelu(a);
        }
        __syncthreads();
        if (tid < 32) {
            const float* W2 = nuW2 + t*(32*32);
            float a = nub2[t*32 + tid];
#pragma unroll
            for (int k2 = 0; k2 < 32; ++k2) a += sU[k2] * W2[k2*32 + tid];
            const float snew = sH[tid] + lrelu(a);
            ws[OFF_S + g*DD + tid] = snew;
            sSnew[tid] = snew;
        }
        __syncthreads();
        if (t < TT-1) {
            if (tid < 128) {
                const int tn = t + 1;
                const int m = slot;   // 0..3
                const float *w1m, *w2m; float* dst;
                if (m == 0)      { w1m = eqW1_ss + tn*FIN*OO;         w2m = eqW2_ss + tn*FIN*OO;         dst = PRJn + P_SASS; }
                else if (m == 1) { w1m = eqW1_ss + tn*FIN*OO + DD*OO; w2m = eqW2_ss + tn*FIN*OO + DD*OO; dst = PRJn + P_SBSS; }
                else if (m == 2) { w1m = eqW1_ps + tn*FIN*OO + DD*OO; w2m = eqW2_ps + tn*FIN*OO + DD*OO; dst = PRJn + P_SBPS; }
                else             { w1m = eqW1_sp + tn*FIN*OO;         w2m = eqW2_sp + tn*FIN*OO;         dst = PRJn + P_SASP; }
                float a = 0.f;
#pragma unroll
                for (int d = 0; d < 32; ++d) a += sSnew[d] * (w1m[d*OO + o] + w2m[d*OO + o]);
                dst[g*OO + o] = a;
            }
        } else {
            if (tid < 64) {   // pool[b] += lrelu(s_new @ p1W + p1b)
                float a = p1b[tid];
#pragma unroll
                for (int d = 0; d < 32; ++d) a += sSnew[d] * p1W[d*MMM + tid];
                atomicAdd(&ws[OFF_POOL + b*MMM + tid], lrelu(a));
            }
            __syncthreads();                  // drain pool atomics
            if (tid == 0) {
                int* ticket = (int*)(ws + OFF_CSR) + TICKET;
                int p = __hip_atomic_fetch_add(ticket, 1, __ATOMIC_ACQ_REL, __HIP_MEMORY_SCOPE_AGENT);
                sWin = (p == 511) ? 1 : 0;
            }
            __syncthreads();
            if (sWin) {
                float* sx = sRed;
                if (tid < 256)
                    sx[tid] = __hip_atomic_load(&ws[OFF_POOL + tid], __ATOMIC_RELAXED, __HIP_MEMORY_SCOPE_AGENT);
                __syncthreads();
                if (tid < 256) {
                    const int b2 = tid >> 6, mm = tid & 63;
                    float a = p2ab[mm];
#pragma unroll
                    for (int k = 0; k < MMM; ++k) a += sx[b2*64 + k] * p2aW[k*MMM + mm];
                    sHy[tid] = lrelu(a);
                }
                __syncthreads();
                if (tid < 256) {
                    const int b2 = tid >> 6, mm = tid & 63;
                    float a = p2bb[mm];
#pragma unroll
                    for (int k = 0; k < MMM; ++k) a += sHy[b2*64 + k] * p2bW[k*MMM + mm];
                    sHz[tid] = lrelu(a);
                }
                __syncthreads();
                if (tid < BB) {
                    float acc2 = p3b[0];
#pragma unroll
                    for (int k = 0; k < MMM; ++k) acc2 += sHz[tid*64 + k] * p3W[k];
                    out[tid] = acc2;
                }
            }
        }
    } else {
        // ================= pore receiver =================
        const int g = blk - 512, b = g >> 4, p = g & 15;
        const float* wa = eqW1_sp + t*FIN*OO + 2*DD*OO + o;
        const float* wb = eqW2_sp + t*FIN*OO + 2*DD*OO + o;
        float we[16];
#pragma unroll
        for (int c = 0; c < 16; ++c) we[c] = wa[c*OO] + wb[c*OO];
        const float bias = eqb_sp[t*OO + o];
        const float awo  = aw_sp[t*OO + o];
        const float abv  = ab_sp[t];
        const float sb   = PRJ[P_PBSP + g*OO + o];
        const float* SAb = PRJ + P_SASP + b*(NN*OO);
        const float* EFb = ws + OFF_BSP + b*(ESP*CC);
        const int cnt = csr[SP_CNT + p];
        const int2* lst = (const int2*)(csr + SP_PAIR) + p*MAXDEG_SP;
        float acc = 0.f;
        for (int k = slot; k < cnt; k += 16) {
            const int2 es = lst[k];
            float a = bias + sb + SAb[es.y*OO + o] + dot16r(EFb + es.x*CC, we);
            float u = lrelu(a);
            float rr = red32(u * awo);
            acc += u / (1.f + expf(-(rr + abv)));
        }
        sRed[slot*32 + o] = acc;
        if (tid < 32) sH[tid] = ws[OFF_SP + g*DD + tid];
        __syncthreads();
        if (tid < 32) {
            float mv = 0.f;
#pragma unroll
            for (int j = 0; j < 16; ++j) mv += sRed[j*32 + tid];
            sH[32 + tid] = mv;
        }
        __syncthreads();
        if (tid < 32) {
            const float* W1 = nupW1 + t*(64*32);
            float a = nupb1[t*32 + tid];
#pragma unroll
            for (int f = 0; f < 64; ++f) a += sH[f] * W1[f*32 + tid];
            sU[tid] = lrelu(a);
        }
        __syncthreads();
        if (tid < 32) {
            const float* W2 = nupW2 + t*(32*32);
            float a = nupb2[t*32 + tid];
#pragma unroll
            for (int k2 = 0; k2 < 32; ++k2) a += sU[k2] * W2[k2*32 + tid];
            const float snew = sH[tid] + lrelu(a);
            ws[OFF_SP + g*DD + tid] = snew;
            sSnew[tid] = snew;
        }
        __syncthreads();
        if (t < TT-1 && tid < 64) {
            const int tn = t + 1;
            const int m = slot;       // 0..1
            const float *w1m, *w2m; float* dst;
            if (m == 0) { w1m = eqW1_ps + tn*FIN*OO;         w2m = eqW2_ps + tn*FIN*OO;         dst = PRJn + P_PAPS; }
            else        { w1m = eqW1_sp + tn*FIN*OO + DD*OO; w2m = eqW2_sp + tn*FIN*OO + DD*OO; dst = PRJn + P_PBSP; }
            float a = 0.f;
#pragma unroll
            for (int d = 0; d < 32; ++d) a += sSnew[d] * (w1m[d*OO + o] + w2m[d*OO + o]);
            dst[g*OO + o] = a;
        }
    }
}

// ---- launch ------------------------------------------------------------
extern "C" void kernel_launch(void* const* d_in, const int* in_sizes, int n_in,
                              void* d_out, int out_size, void* d_ws, size_t ws_size,
                              hipStream_t stream) {
    (void)in_sizes; (void)n_in; (void)out_size; (void)ws_size;
    const float* sites    = (const float*)d_in[0];
    const float* bonds    = (const float*)d_in[1];
    const float* sites_p  = (const float*)d_in[2];
    const float* bonds_sp = (const float*)d_in[3];
    const float* bonds_ps = (const float*)d_in[4];
    const int* idx1    = (const int*)d_in[5];
    const int* idx2    = (const int*)d_in[6];
    const int* idx1_sp = (const int*)d_in[7];
    const int* idx2_sp = (const int*)d_in[8];
    const int* idx1_ps = (const int*)d_in[9];
    const int* idx2_ps = (const int*)d_in[10];
    const float* se_W  = (const float*)d_in[11];
    const float* se_b  = (const float*)d_in[12];
    const float* sep_W = (const float*)d_in[13];
    const float* sep_b = (const float*)d_in[14];
    const float* ee_W  = (const float*)d_in[15];
    const float* ee_b  = (const float*)d_in[16];
    const float* eep_W = (const float*)d_in[17];
    const float* eep_b = (const float*)d_in[18];
    const float* eqW1_ss = (const float*)d_in[19];
    const float* eqW2_ss = (const float*)d_in[20];
    const float* eqb_ss  = (const float*)d_in[21];
    const float* aw_ss   = (const float*)d_in[22];
    const float* ab_ss   = (const float*)d_in[23];
    const float* eqW1_ps = (const float*)d_in[24];
    const float* eqW2_ps = (const float*)d_in[25];
    const float* eqb_ps  = (const float*)d_in[26];
    const float* aw_ps   = (const float*)d_in[27];
    const float* ab_ps   = (const float*)d_in[28];
    const float* eqW1_sp = (const float*)d_in[29];
    const float* eqW2_sp = (const float*)d_in[30];
    const float* eqb_sp  = (const float*)d_in[31];
    const float* aw_sp   = (const float*)d_in[32];
    const float* ab_sp   = (const float*)d_in[33];
    const float* nuW1  = (const float*)d_in[34];
    const float* nub1  = (const float*)d_in[35];
    const float* nuW2  = (const float*)d_in[36];
    const float* nub2  = (const float*)d_in[37];
    const float* nupW1 = (const float*)d_in[38];
    const float* nupb1 = (const float*)d_in[39];
    const float* nupW2 = (const float*)d_in[40];
    const float* nupb2 = (const float*)d_in[41];
    const float* p1W  = (const float*)d_in[42];
    const float* p1b  = (const float*)d_in[43];
    const float* p2aW = (const float*)d_in[44];
    const float* p2ab = (const float*)d_in[45];
    const float* p2bW = (const float*)d_in[46];
    const float* p2bb = (const float*)d_in[47];
    const float* p3W  = (const float*)d_in[48];
    const float* p3b  = (const float*)d_in[49];

    float* ws  = (float*)d_ws;
    float* out = (float*)d_out;

    k_init<<<256, TPB, 0, stream>>>(sites, bonds, sites_p, bonds_sp, bonds_ps,
                                    idx1, idx2, idx1_ps, idx2_ps, idx1_sp, idx2_sp,
                                    se_W, se_b, sep_W, sep_b, ee_W, ee_b, eep_W, eep_b,
                                    eqW1_ss, eqW2_ss, eqW1_ps, eqW2_ps, eqW1_sp, eqW2_sp, ws);
    for (int t = 0; t < TT; ++t) {
        k_step<<<576, SPB, 0, stream>>>(
            eqW1_ss, eqW2_ss, eqb_ss, aw_ss, ab_ss,
            eqW1_ps, eqW2_ps, eqb_ps, aw_ps, ab_ps,
            eqW1_sp, eqW2_sp, eqb_sp, aw_sp, ab_sp,
            nuW1, nub1, nuW2, nub2, nupW1, nupb1, nupW2, nupb2,
            p1W, p1b, p2aW, p2ab, p2bW, p2bb, p3W, p3b,
            ws, out, t);
    }
}